// Round 10
// baseline (159.315 us; speedup 1.0000x reference)
//
#include <hip/hip_runtime.h>

typedef unsigned short u16;
typedef unsigned int u32;
typedef short short8v __attribute__((ext_vector_type(8)));
typedef float float4v __attribute__((ext_vector_type(4)));
typedef unsigned short ushort4v __attribute__((ext_vector_type(4)));
typedef unsigned int uint2v __attribute__((ext_vector_type(2)));
typedef unsigned int uint4v __attribute__((ext_vector_type(4)));

// ---------------- LDS layout (u16 element offsets) ----------------
// Shared: Xs/Ostage [64][200]  (x bf16, later proj input)      = 12800 u16
// Private per wave: arena 2560 u16 (5120 B), sequentially reused:
//   Q or K tile  [64][40]  (2560 u16)   (one head at a time)
//   V^T tile     [32][72]  (2304 u16)
#define XLD2  200
#define QLD2  40
#define VLD2  72
#define ARENA_SZ 2560
#define AR_OFF  12800
#define LDS_U16 (AR_OFF + 4*ARENA_SZ)   // 23040
#define LDS_BYTES (LDS_U16*2)           // 46080 B -> 3 blocks/CU

// scale * log2(e): softmax computed in base-2 domain (bias table premultiplied)
#define SC2 (0.20412414523193154f * 1.4426950408889634f)

__device__ __forceinline__ u16 f2bf(float f){
  unsigned u = __builtin_bit_cast(unsigned, f);
  return (u16)((u + 0x7FFFu + ((u >> 16) & 1u)) >> 16);
}
__device__ __forceinline__ void st4(u16* p, float4v v){
  ushort4v pk = { f2bf(v[0]), f2bf(v[1]), f2bf(v[2]), f2bf(v[3]) };
  *(ushort4v*)p = pk;
}
__device__ __forceinline__ u32 pkbf(float a, float b){
  return (u32)f2bf(a) | ((u32)f2bf(b) << 16);
}

// ---------------- prep: padded qkv weights (HD 24 -> 32, zero rows) + proj ----
// Wq'[part(3)][hp(8)][d(32)][c(192)]: row R = part*256 + hp*32 + d
__global__ void prep_convert(const float* __restrict__ qkv_w, const float* __restrict__ proj_w,
                             u16* __restrict__ Wq, u16* __restrict__ Wp){
  int idx = blockIdx.x*blockDim.x + threadIdx.x;
  const int total = 147456 + 36864;
  for (; idx < total; idx += gridDim.x*blockDim.x){
    if (idx < 147456){
      int R = idx / 192, c = idx - R*192;
      int part = R >> 8, hpd = R & 255, hp = hpd >> 5, d = hpd & 31;
      float v = 0.f;
      if (d < 24) v = qkv_w[(part*192 + (hp>>2)*96 + (hp&3)*24 + d)*192 + c];
      Wq[idx] = f2bf(v);
    } else {
      int j = idx - 147456;
      Wp[j] = f2bf(proj_w[j]);
    }
  }
}

__device__ __forceinline__ void lnrelu6(float* v, const float* g, const float* b){
  float mu = (v[0]+v[1]+v[2]+v[3]+v[4]+v[5]) * (1.0f/6.0f);
  float var = 0.f;
  #pragma unroll
  for (int j=0;j<6;++j){ float d = v[j]-mu; var += d*d; }
  var *= (1.0f/6.0f);
  float inv = rsqrtf(var + 1e-5f);
  #pragma unroll
  for (int j=0;j<6;++j) v[j] = fmaxf((v[j]-mu)*inv*g[j] + b[j], 0.f);
}

// ---------------- prep: rel-pos bias, biasT[(i*4+h)][n=query][m=key], *log2e ---
__global__ void prep_bias(const float* __restrict__ ppw, const float* __restrict__ ppb,
                          const float* __restrict__ ln1g, const float* __restrict__ ln1b,
                          const float* __restrict__ fc1w, const float* __restrict__ fc1b,
                          const float* __restrict__ ln2g, const float* __restrict__ ln2b,
                          const float* __restrict__ fc2w, const float* __restrict__ fc2b,
                          const float* __restrict__ ln3g, const float* __restrict__ ln3b,
                          const float* __restrict__ fc3w, const float* __restrict__ fc3b,
                          float* __restrict__ biasT){
  __shared__ float pos3[2][225][4];
  const int t = threadIdx.x;
  if (t < 225){
    const float dy = (float)(t/15) - 7.0f;
    const float dx = (float)(t%15) - 7.0f;
    for (int i=0;i<2;++i){
      float v[6], y[6];
      #pragma unroll
      for (int j=0;j<6;++j)
        v[j] = dy*ppw[(i*6+j)*2+0] + dx*ppw[(i*6+j)*2+1] + ppb[i*6+j];
      lnrelu6(v, ln1g+i*6, ln1b+i*6);
      #pragma unroll
      for (int j=0;j<6;++j){
        float a = fc1b[i*6+j];
        #pragma unroll
        for (int k=0;k<6;++k) a += v[k]*fc1w[(i*6+j)*6+k];
        y[j] = a;
      }
      lnrelu6(y, ln2g+i*6, ln2b+i*6);
      #pragma unroll
      for (int j=0;j<6;++j){
        float a = fc2b[i*6+j];
        #pragma unroll
        for (int k=0;k<6;++k) a += y[k]*fc2w[(i*6+j)*6+k];
        v[j] = a;
      }
      lnrelu6(v, ln3g+i*6, ln3b+i*6);
      #pragma unroll
      for (int h=0;h<4;++h){
        float a = fc3b[i*4+h];
        #pragma unroll
        for (int k=0;k<6;++k) a += v[k]*fc3w[(i*4+h)*6+k];
        pos3[i][t][h] = a * 1.4426950408889634f;
      }
    }
  }
  __syncthreads();
  for (int idx = t; idx < 32768; idx += 256){
    int i  = idx >> 14;
    int hh = (idx >> 12) & 3;
    int n  = (idx >> 6) & 63;
    int m  = idx & 63;
    int tt = (((n>>3)-(m>>3)+7)*15) + ((n&7)-(m&7)+7);
    biasT[idx] = pos3[i][tt][hh];
  }
}

// ---------------- fused main: 1 window/block, 4 waves, 3 barriers ----------------
__global__ __launch_bounds__(256, 3) void awa_main(
    const float* __restrict__ x, const u16* __restrict__ Wq,
    const u16* __restrict__ Wp, const float* __restrict__ proj_b,
    const float* __restrict__ biasT, float* __restrict__ out){
  extern __shared__ u16 lds[];
  const int tid  = threadIdx.x;
  const int wave = tid >> 6;
  const int lane = tid & 63;
  const int g    = lane >> 4;
  const int q16  = lane & 15;
  const int bid  = blockIdx.x;
  const int b    = bid >> 10;
  const int win  = bid & 1023;
  const int h1   = win >> 5, w1 = win & 31;
  const size_t xbase = ((size_t)b*65536u + (size_t)(h1*8)*256u + (size_t)(w1*8)) * 192u;
  u16* arena = &lds[AR_OFF + wave*ARENA_SZ];

  // ---- P0: stage x window -> bf16 Xs [64][200] ----
  {
    float4v xr[12];
    #pragma unroll
    for (int it=0; it<12; ++it){
      int f = (tid + it*256) << 2;
      int rr = f/1536, rem = f - rr*1536, ss = rem/192, cc = rem - ss*192;
      xr[it] = *(const float4v*)(x + xbase + (size_t)((rr*256+ss)*192+cc));
    }
    #pragma unroll
    for (int it=0; it<12; ++it){
      int f = (tid + it*256) << 2;
      int rr = f/1536, rem = f - rr*1536, ss = rem/192, cc = rem - ss*192;
      st4(&lds[(rr*8+ss)*XLD2 + cc], xr[it]);
    }
  }
  __syncthreads();   // B1: Xs visible (read-only until B2)

  // bpermute indices for in-register P redistribution:
  // dest (q16,g) elem e: key = kc*32+g*8+e; src lane = q16 + 16*(2*(g&1) + e/4),
  // kt = 2*kc + (g>>1)  [verified element-wise]
  const int idxA = (((lane & 15) | ((lane & 16) << 1))) << 2;
  const int idxB = idxA + 64;
  const bool hi2 = (lane & 32) != 0;   // g>=2 -> kt = 2kc+1

  uint2v po[2][2][4];   // [h][dt][mt] packed bf16 O^T fragments

  #pragma unroll
  for (int h = 0; h < 2; ++h){
    const int hp = h*4 + wave;
    short8v qf[4], kf[4], vf[2][2];

    // ---- Q and K sweeps (part 0,1): private arena [64][40] ----
    #pragma unroll
    for (int part = 0; part < 2; ++part){
      float4v acc[2][4];
      #pragma unroll
      for (int tq=0;tq<2;++tq)
        #pragma unroll
        for (int mt=0;mt<4;++mt) acc[tq][mt] = (float4v){0.f,0.f,0.f,0.f};
      const u16* w0 = Wq + (size_t)(part*256 + hp*32 + q16)*192 + g*8;
      const u16* w1 = w0 + (size_t)16*192;
      short8v wa0 = *(const short8v*)w0;
      short8v wa1 = *(const short8v*)w1;
      #pragma unroll
      for (int kc = 0; kc < 6; ++kc){
        short8v wb0, wb1;
        if (kc < 5){ wb0 = *(const short8v*)(w0 + (kc+1)*32); wb1 = *(const short8v*)(w1 + (kc+1)*32); }
        short8v xs[4];
        #pragma unroll
        for (int mt=0;mt<4;++mt)
          xs[mt] = *(const short8v*)&lds[(mt*16+q16)*XLD2 + kc*32 + g*8];
        #pragma unroll
        for (int mt=0;mt<4;++mt){
          acc[0][mt] = __builtin_amdgcn_mfma_f32_16x16x32_bf16(wa0, xs[mt], acc[0][mt], 0,0,0);
          acc[1][mt] = __builtin_amdgcn_mfma_f32_16x16x32_bf16(wa1, xs[mt], acc[1][mt], 0,0,0);
        }
        wa0 = wb0; wa1 = wb1;
      }
      // store [tok][ch(32)] then read frags (same-wave in-order LDS)
      #pragma unroll
      for (int tq=0;tq<2;++tq)
        #pragma unroll
        for (int mt=0;mt<4;++mt)
          st4(&arena[(mt*16+q16)*QLD2 + tq*16 + g*4], acc[tq][mt]);
      asm volatile("" ::: "memory");
      #pragma unroll
      for (int mt=0;mt<4;++mt){
        short8v fr = *(const short8v*)&arena[(mt*16+q16)*QLD2 + g*8];
        if (part == 0) qf[mt] = fr; else kf[mt] = fr;
      }
      asm volatile("" ::: "memory");
    }

    // ---- V sweep (part 2): V^T [32 d][72 tok] in arena ----
    {
      float4v acc[2][4];
      #pragma unroll
      for (int tv=0;tv<2;++tv)
        #pragma unroll
        for (int mt=0;mt<4;++mt) acc[tv][mt] = (float4v){0.f,0.f,0.f,0.f};
      const u16* w0 = Wq + (size_t)(2*256 + hp*32 + q16)*192 + g*8;
      const u16* w1 = w0 + (size_t)16*192;
      short8v wa0 = *(const short8v*)w0;
      short8v wa1 = *(const short8v*)w1;
      #pragma unroll
      for (int kc = 0; kc < 6; ++kc){
        short8v wb0, wb1;
        if (kc < 5){ wb0 = *(const short8v*)(w0 + (kc+1)*32); wb1 = *(const short8v*)(w1 + (kc+1)*32); }
        short8v xs[4];
        #pragma unroll
        for (int mt=0;mt<4;++mt)
          xs[mt] = *(const short8v*)&lds[(mt*16+q16)*XLD2 + kc*32 + g*8];
        #pragma unroll
        for (int mt=0;mt<4;++mt){
          acc[0][mt] = __builtin_amdgcn_mfma_f32_16x16x32_bf16(xs[mt], wa0, acc[0][mt], 0,0,0);
          acc[1][mt] = __builtin_amdgcn_mfma_f32_16x16x32_bf16(xs[mt], wa1, acc[1][mt], 0,0,0);
        }
        wa0 = wb0; wa1 = wb1;
      }
      #pragma unroll
      for (int tv=0;tv<2;++tv)
        #pragma unroll
        for (int mt=0;mt<4;++mt)
          st4(&arena[(tv*16+q16)*VLD2 + mt*16 + g*4], acc[tv][mt]);
      asm volatile("" ::: "memory");
      #pragma unroll
      for (int dt=0;dt<2;++dt)
        #pragma unroll
        for (int kc=0;kc<2;++kc)
          vf[dt][kc] = *(const short8v*)&arena[(dt*16+q16)*VLD2 + kc*32 + g*8];
      asm volatile("" ::: "memory");
    }

    // ---- attention: per-mt QK^T -> softmax(exp2) -> in-reg P -> PV ----
    const float* bt = biasT + hp*4096;
    #pragma unroll
    for (int mt=0; mt<4; ++mt){
      float4v bv[4];
      #pragma unroll
      for (int kt=0;kt<4;++kt)
        bv[kt] = *(const float4v*)&bt[(mt*16+q16)*64 + kt*16 + g*4];
      float4v s[4];
      #pragma unroll
      for (int kt=0;kt<4;++kt) s[kt] = (float4v){0.f,0.f,0.f,0.f};
      #pragma unroll
      for (int kt=0;kt<4;++kt)
        s[kt] = __builtin_amdgcn_mfma_f32_16x16x32_bf16(kf[kt], qf[mt], s[kt], 0,0,0);
      #pragma unroll
      for (int kt=0;kt<4;++kt) s[kt] = s[kt]*SC2 + bv[kt];
      float mx = s[0][0];
      #pragma unroll
      for (int kt=0;kt<4;++kt)
        #pragma unroll
        for (int r=0;r<4;++r) mx = fmaxf(mx, s[kt][r]);
      mx = fmaxf(mx, __shfl_xor(mx, 16));
      mx = fmaxf(mx, __shfl_xor(mx, 32));
      float sum = 0.f;
      u32 pklo[4], pkhi[4];
      #pragma unroll
      for (int kt=0;kt<4;++kt){
        float e0 = exp2f(s[kt][0]-mx), e1 = exp2f(s[kt][1]-mx);
        float e2 = exp2f(s[kt][2]-mx), e3 = exp2f(s[kt][3]-mx);
        sum += (e0+e1)+(e2+e3);
        pklo[kt] = pkbf(e0, e1);
        pkhi[kt] = pkbf(e2, e3);
      }
      sum += __shfl_xor(sum, 16);
      sum += __shfl_xor(sum, 32);
      const float inv = 1.0f / sum;
      float4v o0 = (float4v){0.f,0.f,0.f,0.f};
      float4v o1 = (float4v){0.f,0.f,0.f,0.f};
      #pragma unroll
      for (int kc=0;kc<2;++kc){
        u32 a0 = (u32)__builtin_amdgcn_ds_bpermute(idxA, (int)pklo[2*kc]);
        u32 a1 = (u32)__builtin_amdgcn_ds_bpermute(idxA, (int)pkhi[2*kc]);
        u32 b0 = (u32)__builtin_amdgcn_ds_bpermute(idxB, (int)pklo[2*kc]);
        u32 b1 = (u32)__builtin_amdgcn_ds_bpermute(idxB, (int)pkhi[2*kc]);
        u32 c0 = (u32)__builtin_amdgcn_ds_bpermute(idxA, (int)pklo[2*kc+1]);
        u32 c1 = (u32)__builtin_amdgcn_ds_bpermute(idxA, (int)pkhi[2*kc+1]);
        u32 d0 = (u32)__builtin_amdgcn_ds_bpermute(idxB, (int)pklo[2*kc+1]);
        u32 d1 = (u32)__builtin_amdgcn_ds_bpermute(idxB, (int)pkhi[2*kc+1]);
        uint4v uv = { hi2 ? c0 : a0, hi2 ? c1 : a1, hi2 ? d0 : b0, hi2 ? d1 : b1 };
        short8v pf = __builtin_bit_cast(short8v, uv);
        o0 = __builtin_amdgcn_mfma_f32_16x16x32_bf16(vf[0][kc], pf, o0, 0,0,0);
        o1 = __builtin_amdgcn_mfma_f32_16x16x32_bf16(vf[1][kc], pf, o1, 0,0,0);
      }
      o0 *= inv; o1 *= inv;
      po[h][0][mt] = (uint2v){ pkbf(o0[0], o0[1]), pkbf(o0[2], o0[3]) };
      po[h][1][mt] = (uint2v){ pkbf(o1[0], o1[1]), pkbf(o1[2], o1[3]) };
    }
  }
  __syncthreads();   // B2: all Xs reads + arena use done -> Ostage may overlay Xs

  // ---- Ostage [64][200] (cols 0..191): O^T fragments, d<24 only ----
  #pragma unroll
  for (int h=0; h<2; ++h){
    const int cb = h*96 + wave*24;
    #pragma unroll
    for (int dt=0; dt<2; ++dt){
      if (dt==0 || g<2){
        #pragma unroll
        for (int mt=0; mt<4; ++mt)
          *(uint2v*)&lds[(mt*16+q16)*XLD2 + cb + dt*16 + g*4] = po[h][dt][mt];
      }
    }
  }
  __syncthreads();   // B3: Ostage visible

  // ---- proj: out = Ostage @ Wp^T + b (per-kc reload, W double-buffered) ----
  #pragma unroll
  for (int t=0; t<3; ++t){
    const int nt = wave + t*4;
    const u16* wb = Wp + (size_t)(nt*16 + q16)*192 + g*8;
    float4v acc[4];
    #pragma unroll
    for (int mt=0;mt<4;++mt) acc[mt] = (float4v){0.f,0.f,0.f,0.f};
    short8v wa = *(const short8v*)wb;
    #pragma unroll
    for (int kc=0; kc<6; ++kc){
      short8v wn;
      if (kc < 5) wn = *(const short8v*)(wb + (kc+1)*32);
      short8v a2[4];
      #pragma unroll
      for (int mt=0;mt<4;++mt)
        a2[mt] = *(const short8v*)&lds[(mt*16+q16)*XLD2 + kc*32 + g*8];
      #pragma unroll
      for (int mt=0; mt<4; ++mt)
        acc[mt] = __builtin_amdgcn_mfma_f32_16x16x32_bf16(wa, a2[mt], acc[mt], 0,0,0);
      wa = wn;
    }
    const int j0 = nt*16 + g*4;
    const float4v pb = *(const float4v*)(proj_b + j0);
    #pragma unroll
    for (int mt=0; mt<4; ++mt){
      const int tok = mt*16 + q16;
      const int l = ((h1*8 + (tok>>3)) << 8) + w1*8 + (tok & 7);
      float4v res = acc[mt] + pb;
      *(float4v*)(out + ((size_t)b*65536u + (size_t)l)*192u + j0) = res;
    }
  }
}

extern "C" void kernel_launch(void* const* d_in, const int* in_sizes, int n_in,
                              void* d_out, int out_size, void* d_ws, size_t ws_size,
                              hipStream_t stream){
  const float* x      = (const float*)d_in[0];
  const float* qkv_w  = (const float*)d_in[1];
  const float* proj_w = (const float*)d_in[2];
  const float* proj_b = (const float*)d_in[3];
  const float* ppw    = (const float*)d_in[4];
  const float* ppb    = (const float*)d_in[5];
  const float* ln1g   = (const float*)d_in[6];
  const float* ln1b   = (const float*)d_in[7];
  const float* fc1w   = (const float*)d_in[8];
  const float* fc1b   = (const float*)d_in[9];
  const float* ln2g   = (const float*)d_in[10];
  const float* ln2b   = (const float*)d_in[11];
  const float* fc2w   = (const float*)d_in[12];
  const float* fc2b   = (const float*)d_in[13];
  const float* ln3g   = (const float*)d_in[14];
  const float* ln3b   = (const float*)d_in[15];
  const float* fc3w   = (const float*)d_in[16];
  const float* fc3b   = (const float*)d_in[17];

  u16*   Wq    = (u16*)d_ws;                       // padded 768x192 = 147456 bf16
  u16*   Wp    = Wq + 147456;                      // 36864 bf16
  float* biasT = (float*)((char*)d_ws + 368640);   // 32768 f32

  prep_convert<<<180, 256, 0, stream>>>(qkv_w, proj_w, Wq, Wp);
  prep_bias<<<1, 256, 0, stream>>>(ppw, ppb, ln1g, ln1b, fc1w, fc1b,
                                   ln2g, ln2b, fc2w, fc2b, ln3g, ln3b,
                                   fc3w, fc3b, biasT);
  awa_main<<<2048, 256, LDS_BYTES, stream>>>(x, Wq, Wp, proj_b, biasT, (float*)d_out);
}